// Round 1
// baseline (927.042 us; speedup 1.0000x reference)
//
#include <hip/hip_runtime.h>
#include <hip/hip_bf16.h>
#include <stdint.h>

#define NE 131072
#define CHUNK 65536

typedef __attribute__((ext_vector_type(8))) short bf16x8;
typedef __attribute__((ext_vector_type(4))) float f32x4;

__device__ __forceinline__ unsigned short f2bf(float f) {
  unsigned u = __float_as_uint(f);
  u += 0x7FFF + ((u >> 16) & 1);   // round-to-nearest-even
  return (unsigned short)(u >> 16);
}
__device__ __forceinline__ float bf2f(unsigned short h) {
  return __uint_as_float((unsigned)h << 16);
}

__device__ __forceinline__ void gload_lds16(const void* g, void* l) {
  __builtin_amdgcn_global_load_lds(
      (const __attribute__((address_space(1))) unsigned*)g,
      (__attribute__((address_space(3))) unsigned*)l, 16, 0, 0);
}

// dst[p][n][k] = bf16(src[p][k][n]);  src fp32 [P][K][Nc], dst bf16 [P][Nc][K]
__global__ void transpose_cvt(const float* __restrict__ src,
                              unsigned short* __restrict__ dst,
                              int K, int Nc) {
  int p = blockIdx.y;
  long base = (long)p * K * Nc;
  int tot = K * Nc;
  for (int i = blockIdx.x * blockDim.x + threadIdx.x; i < tot;
       i += gridDim.x * blockDim.x) {
    int n = i / K, k = i - n * K;
    dst[base + i] = f2bf(src[base + (long)k * Nc + n]);
  }
}

// Xb = bf16(relu(x)), vectorized 4 elems/thread
__global__ void relu_cvt_x(const float4* __restrict__ x,
                           ushort4* __restrict__ xb) {
  int i = blockIdx.x * blockDim.x + threadIdx.x;
  float4 v = x[i];
  ushort4 o;
  o.x = f2bf(fmaxf(v.x, 0.f));
  o.y = f2bf(fmaxf(v.y, 0.f));
  o.z = f2bf(fmaxf(v.z, 0.f));
  o.w = f2bf(fmaxf(v.w, 0.f));
  xb[i] = o;
}

// C[M x Nc] = A[M x K](bf16) * Bt[Nc x K](bf16)^T + bias
// epilogue: optional fp32 store (outF), optional bf16(relu) store (outA)
// 128x128 tile, 4 waves in 2x2, BK=32, global_load_lds staging (m97 structure)
__global__ __launch_bounds__(256, 2) void gemm_bf16(
    const unsigned short* __restrict__ A,
    const unsigned short* __restrict__ Bt,
    const float* __restrict__ bias,
    float* __restrict__ outF,
    unsigned short* __restrict__ outA,
    int K, int Nc) {
  __shared__ unsigned short As[128 * 32];
  __shared__ unsigned short Bs[128 * 32];
  const int tid = threadIdx.x;
  const int wave = tid >> 6, lane = tid & 63;
  const int wr = wave >> 1, wc = wave & 1;
  const int lr = lane & 15, lh = lane >> 4;
  const long row0 = (long)blockIdx.x * 128;
  const int col0 = blockIdx.y * 128;

  f32x4 acc[4][4];
#pragma unroll
  for (int m = 0; m < 4; ++m)
#pragma unroll
    for (int n = 0; n < 4; ++n) acc[m][n] = (f32x4){0.f, 0.f, 0.f, 0.f};

  const int nk = K >> 5;
  for (int kt = 0; kt < nk; ++kt) {
    const int k0 = kt << 5;
#pragma unroll
    for (int i = 0; i < 2; ++i) {
      int c = i * 256 + wave * 64 + lane;      // chunk id, 16B each
      int r = c >> 2, k8 = (c & 3) * 8;
      gload_lds16(A + (row0 + r) * K + k0 + k8, &As[(i * 256 + wave * 64) * 8]);
      gload_lds16(Bt + (long)(col0 + r) * K + k0 + k8,
                  &Bs[(i * 256 + wave * 64) * 8]);
    }
    __syncthreads();   // drains vmcnt before barrier (compiler-emitted)
    bf16x8 af[4], bfr[4];
#pragma unroll
    for (int m = 0; m < 4; ++m)
      af[m] = *(const bf16x8*)&As[(wr * 64 + m * 16 + lr) * 32 + lh * 8];
#pragma unroll
    for (int n = 0; n < 4; ++n)
      bfr[n] = *(const bf16x8*)&Bs[(wc * 64 + n * 16 + lr) * 32 + lh * 8];
#pragma unroll
    for (int m = 0; m < 4; ++m)
#pragma unroll
      for (int n = 0; n < 4; ++n)
        acc[m][n] =
            __builtin_amdgcn_mfma_f32_16x16x32_bf16(af[m], bfr[n], acc[m][n], 0, 0, 0);
    __syncthreads();
  }

  float bv[4];
#pragma unroll
  for (int n = 0; n < 4; ++n) bv[n] = bias[col0 + wc * 64 + n * 16 + lr];
#pragma unroll
  for (int m = 0; m < 4; ++m) {
    long rbase = row0 + wr * 64 + m * 16 + lh * 4;
#pragma unroll
    for (int r = 0; r < 4; ++r) {
      long rr = rbase + r;
#pragma unroll
      for (int n = 0; n < 4; ++n) {
        int cc = col0 + wc * 64 + n * 16 + lr;
        float v = acc[m][n][r] + bv[n];
        if (outF) outF[rr * Nc + cc] = v;
        if (outA) outA[rr * Nc + cc] = f2bf(fmaxf(v, 0.f));
      }
    }
  }
}

// final layer: logit = relu(S1[n,:]) . w + sb2 ; sigmoid/clip/ratio/mask
// 16 lanes per event, 16 events per 256-thread block
__global__ void head_kernel(const unsigned short* __restrict__ S1,  // [CHUNK x 256]
                            const unsigned short* __restrict__ w,   // [256]
                            const float* __restrict__ Sb2,          // [3]
                            const int* __restrict__ y,
                            const int* __restrict__ pairs,          // [3][2]
                            int p, int r0,
                            float* __restrict__ outR,
                            float* __restrict__ outS,
                            float* __restrict__ outM) {
  int lane = threadIdx.x & 63;
  int wave = threadIdx.x >> 6;
  int sub = lane & 15;
  int nloc = blockIdx.x * 16 + wave * 4 + (lane >> 4);
  const unsigned short* row = S1 + (long)nloc * 256 + sub * 16;
  const unsigned short* wp = w + sub * 16;
  float accum = 0.f;
#pragma unroll
  for (int j = 0; j < 2; ++j) {
    bf16x8 a = *(const bf16x8*)(row + j * 8);
    bf16x8 b = *(const bf16x8*)(wp + j * 8);
#pragma unroll
    for (int e = 0; e < 8; ++e)
      accum += fmaxf(bf2f((unsigned short)a[e]), 0.f) * bf2f((unsigned short)b[e]);
  }
#pragma unroll
  for (int off = 1; off < 16; off <<= 1) accum += __shfl_xor(accum, off);
  if (sub == 0) {
    long n = (long)r0 + nloc;
    float logit = accum + Sb2[p];
    float s = 1.f / (1.f + expf(-logit));
    s = fmaxf(s, 1e-9f);
    float r = (1.f - s) / s;
    int yv = y[n];
    float mf = (yv == pairs[p * 2] || yv == pairs[p * 2 + 1]) ? 1.f : 0.f;
    outR[(long)p * NE + n] = r * mf;
    outS[(long)p * NE + n] = s * mf;
    outM[(long)p * NE + n] = mf;
  }
}

extern "C" void kernel_launch(void* const* d_in, const int* in_sizes, int n_in,
                              void* d_out, int out_size, void* d_ws, size_t ws_size,
                              hipStream_t stream) {
  const float* x   = (const float*)d_in[0];
  const int*   y   = (const int*)d_in[1];
  const int*   prs = (const int*)d_in[2];
  const float* W0  = (const float*)d_in[3];
  const float* b0  = (const float*)d_in[4];
  const float* W1  = (const float*)d_in[5];
  const float* b1  = (const float*)d_in[6];
  const float* W2  = (const float*)d_in[7];
  const float* b2  = (const float*)d_in[8];
  const float* SW0 = (const float*)d_in[9];
  const float* Sb0 = (const float*)d_in[10];
  const float* SW1 = (const float*)d_in[11];
  const float* Sb1 = (const float*)d_in[12];
  const float* SW2 = (const float*)d_in[13];
  const float* Sb2 = (const float*)d_in[14];

  uint8_t* ws = (uint8_t*)d_ws;
  size_t off = 0;
  auto take = [&](size_t bytes) -> void* {
    void* ptr = ws + off;
    off = (off + bytes + 255) & ~(size_t)255;
    return ptr;
  };
  unsigned short* W0t  = (unsigned short*)take((size_t)64 * 512 * 2);
  unsigned short* W1t  = (unsigned short*)take((size_t)512 * 512 * 2);
  unsigned short* W2t  = (unsigned short*)take((size_t)512 * 512 * 2);
  unsigned short* SW0t = (unsigned short*)take((size_t)3 * 512 * 512 * 2);
  unsigned short* SW1t = (unsigned short*)take((size_t)3 * 256 * 512 * 2);
  unsigned short* SW2b = (unsigned short*)take((size_t)3 * 256 * 2);
  unsigned short* Xb   = (unsigned short*)take((size_t)NE * 64 * 2);
  unsigned short* bufR = (unsigned short*)take((size_t)CHUNK * 512 * 2);
  unsigned short* bufA = (unsigned short*)take((size_t)CHUNK * 512 * 2);
  unsigned short* bufB = (unsigned short*)take((size_t)CHUNK * 512 * 2);

  float* out   = (float*)d_out;
  float* outRe = out;
  float* outR  = out + (size_t)NE * 512;
  float* outS  = outR + (size_t)3 * NE;
  float* outM  = outS + (size_t)3 * NE;

  // ---- prep: weights -> bf16 transposed, x -> relu bf16 ----
  transpose_cvt<<<dim3(128, 1), 256, 0, stream>>>(W0, W0t, 64, 512);
  transpose_cvt<<<dim3(1024, 1), 256, 0, stream>>>(W1, W1t, 512, 512);
  transpose_cvt<<<dim3(1024, 1), 256, 0, stream>>>(W2, W2t, 512, 512);
  transpose_cvt<<<dim3(1024, 3), 256, 0, stream>>>(SW0, SW0t, 512, 512);
  transpose_cvt<<<dim3(512, 3), 256, 0, stream>>>(SW1, SW1t, 512, 256);
  transpose_cvt<<<dim3(1, 3), 256, 0, stream>>>(SW2, SW2b, 256, 1);
  relu_cvt_x<<<dim3(NE * 64 / 4 / 256), 256, 0, stream>>>((const float4*)x,
                                                          (ushort4*)Xb);

  for (int c = 0; c < NE / CHUNK; ++c) {
    size_t r0 = (size_t)c * CHUNK;
    // trunk
    gemm_bf16<<<dim3(CHUNK / 128, 4), 256, 0, stream>>>(
        Xb + r0 * 64, W0t, b0, nullptr, bufA, 64, 512);
    gemm_bf16<<<dim3(CHUNK / 128, 4), 256, 0, stream>>>(
        bufA, W1t, b1, nullptr, bufB, 512, 512);
    gemm_bf16<<<dim3(CHUNK / 128, 4), 256, 0, stream>>>(
        bufB, W2t, b2, outRe + r0 * 512, bufR, 512, 512);
    // per-pair subnets
    for (int p = 0; p < 3; ++p) {
      gemm_bf16<<<dim3(CHUNK / 128, 4), 256, 0, stream>>>(
          bufR, SW0t + (size_t)p * 512 * 512, Sb0 + (size_t)p * 512, nullptr,
          bufA, 512, 512);
      gemm_bf16<<<dim3(CHUNK / 128, 2), 256, 0, stream>>>(
          bufA, SW1t + (size_t)p * 256 * 512, Sb1 + (size_t)p * 256, nullptr,
          bufB, 512, 256);
      head_kernel<<<dim3(CHUNK / 16), 256, 0, stream>>>(
          bufB, SW2b + p * 256, Sb2, y, prs, p, (int)r0, outR, outS, outM);
    }
  }
}

// Round 2
// 766.987 us; speedup vs baseline: 1.2087x; 1.2087x over previous
//
#include <hip/hip_runtime.h>
#include <hip/hip_bf16.h>
#include <stdint.h>

#define NE 131072
#define CHUNK 32768

typedef __attribute__((ext_vector_type(8))) short bf16x8;
typedef __attribute__((ext_vector_type(4))) float f32x4;

__device__ __forceinline__ unsigned short f2bf(float f) {
  unsigned u = __float_as_uint(f);
  u += 0x7FFF + ((u >> 16) & 1);   // round-to-nearest-even
  return (unsigned short)(u >> 16);
}
__device__ __forceinline__ float bf2f(unsigned short h) {
  return __uint_as_float((unsigned)h << 16);
}

__device__ __forceinline__ void gload_lds16(const void* g, void* l) {
  __builtin_amdgcn_global_load_lds(
      (const __attribute__((address_space(1))) unsigned*)g,
      (__attribute__((address_space(3))) unsigned*)l, 16, 0, 0);
}

// dst[p][n][k] = bf16(src[p][k][n]);  src fp32 [P][K][Nc], dst bf16 [P][Nc][K]
__global__ void transpose_cvt(const float* __restrict__ src,
                              unsigned short* __restrict__ dst,
                              int K, int Nc) {
  int p = blockIdx.y;
  long base = (long)p * K * Nc;
  int tot = K * Nc;
  for (int i = blockIdx.x * blockDim.x + threadIdx.x; i < tot;
       i += gridDim.x * blockDim.x) {
    int n = i / K, k = i - n * K;
    dst[base + i] = f2bf(src[base + (long)k * Nc + n]);
  }
}

// Xb = bf16(relu(x)), vectorized 4 elems/thread
__global__ void relu_cvt_x(const float4* __restrict__ x,
                           ushort4* __restrict__ xb) {
  int i = blockIdx.x * blockDim.x + threadIdx.x;
  float4 v = x[i];
  ushort4 o;
  o.x = f2bf(fmaxf(v.x, 0.f));
  o.y = f2bf(fmaxf(v.y, 0.f));
  o.z = f2bf(fmaxf(v.z, 0.f));
  o.w = f2bf(fmaxf(v.w, 0.f));
  xb[i] = o;
}

// C[M x Nc] = A[M x K](bf16) * Bt[Nc x K](bf16)^T + bias
// grouped over blockIdx.z via element strides; epilogue: optional fp32 store,
// optional bf16(relu) store. 128x128 tile, 4 waves 2x2, BK=32 (m97 structure).
__global__ __launch_bounds__(256, 2) void gemm_bf16(
    const unsigned short* __restrict__ A, long aZ,
    const unsigned short* __restrict__ Bt, long bZ,
    const float* __restrict__ bias, long biasZ,
    float* __restrict__ outF,
    unsigned short* __restrict__ outA, long cZ,
    int K, int Nc) {
  __shared__ unsigned short As[128 * 32];
  __shared__ unsigned short Bs[128 * 32];
  const int z = blockIdx.z;
  A += (long)z * aZ;
  Bt += (long)z * bZ;
  bias += (long)z * biasZ;
  if (outF) outF += (long)z * cZ;
  if (outA) outA += (long)z * cZ;

  const int tid = threadIdx.x;
  const int wave = tid >> 6, lane = tid & 63;
  const int wr = wave >> 1, wc = wave & 1;
  const int lr = lane & 15, lh = lane >> 4;
  const long row0 = (long)blockIdx.x * 128;
  const int col0 = blockIdx.y * 128;

  f32x4 acc[4][4];
#pragma unroll
  for (int m = 0; m < 4; ++m)
#pragma unroll
    for (int n = 0; n < 4; ++n) acc[m][n] = (f32x4){0.f, 0.f, 0.f, 0.f};

  const int nk = K >> 5;
  for (int kt = 0; kt < nk; ++kt) {
    const int k0 = kt << 5;
#pragma unroll
    for (int i = 0; i < 2; ++i) {
      int c = i * 256 + wave * 64 + lane;      // chunk id, 16B each
      int r = c >> 2, k8 = (c & 3) * 8;
      gload_lds16(A + (row0 + r) * K + k0 + k8, &As[(i * 256 + wave * 64) * 8]);
      gload_lds16(Bt + (long)(col0 + r) * K + k0 + k8,
                  &Bs[(i * 256 + wave * 64) * 8]);
    }
    __syncthreads();
    bf16x8 af[4], bfr[4];
#pragma unroll
    for (int m = 0; m < 4; ++m)
      af[m] = *(const bf16x8*)&As[(wr * 64 + m * 16 + lr) * 32 + lh * 8];
#pragma unroll
    for (int n = 0; n < 4; ++n)
      bfr[n] = *(const bf16x8*)&Bs[(wc * 64 + n * 16 + lr) * 32 + lh * 8];
#pragma unroll
    for (int m = 0; m < 4; ++m)
#pragma unroll
      for (int n = 0; n < 4; ++n)
        acc[m][n] =
            __builtin_amdgcn_mfma_f32_16x16x32_bf16(af[m], bfr[n], acc[m][n], 0, 0, 0);
    __syncthreads();
  }

  float bv[4];
#pragma unroll
  for (int n = 0; n < 4; ++n) bv[n] = bias[col0 + wc * 64 + n * 16 + lr];
#pragma unroll
  for (int m = 0; m < 4; ++m) {
    long rbase = row0 + wr * 64 + m * 16 + lh * 4;
#pragma unroll
    for (int r = 0; r < 4; ++r) {
      long rr = rbase + r;
#pragma unroll
      for (int n = 0; n < 4; ++n) {
        int cc = col0 + wc * 64 + n * 16 + lr;
        float v = acc[m][n][r] + bv[n];
        if (outF) outF[rr * Nc + cc] = v;
        if (outA) outA[rr * Nc + cc] = f2bf(fmaxf(v, 0.f));
      }
    }
  }
}

// SW1 GEMM (K=512, Nc=256) with the 256->1 head fused in the epilogue.
// BM=128 x BN=256 in ONE block (8 waves, 2x4). blockIdx.z = pair p.
// logit[row] = sum_cc relu(h1[row,cc]) * w2[cc] + sb2; then sigmoid/ratio/mask.
__global__ __launch_bounds__(512) void gemm_sw1_head(
    const unsigned short* __restrict__ A3,   // [P][CHUNK][512]
    const unsigned short* __restrict__ SW1t, // [P][256][512]
    const float* __restrict__ Sb1,           // [P][256]
    const unsigned short* __restrict__ W2b,  // [P][256]
    const float* __restrict__ Sb2,           // [P]
    const int* __restrict__ y,
    const int* __restrict__ pairs,           // [3][2]
    int r0,
    float* __restrict__ outR, float* __restrict__ outS,
    float* __restrict__ outM) {
  __shared__ unsigned short As[128 * 32];   // 8 KB
  __shared__ unsigned short Bs[256 * 32];   // 16 KB
  __shared__ float part[4][128];            // 2 KB

  const int p = blockIdx.z;
  const unsigned short* A = A3 + (long)p * CHUNK * 512;
  const unsigned short* Bt = SW1t + (long)p * 256 * 512;
  const float* bias = Sb1 + p * 256;
  const unsigned short* w2 = W2b + p * 256;

  const int tid = threadIdx.x;
  const int wave = tid >> 6, lane = tid & 63;
  const int wr = wave >> 2, wc = wave & 3;
  const int lr = lane & 15, lh = lane >> 4;
  const long row0 = (long)blockIdx.x * 128;

  f32x4 acc[4][4];
#pragma unroll
  for (int m = 0; m < 4; ++m)
#pragma unroll
    for (int n = 0; n < 4; ++n) acc[m][n] = (f32x4){0.f, 0.f, 0.f, 0.f};

  for (int kt = 0; kt < 16; ++kt) {
    const int k0 = kt << 5;
    // A tile: 128x32 = 512 16B-chunks, one per thread
    gload_lds16(A + (row0 + (tid >> 2)) * 512 + k0 + (tid & 3) * 8,
                &As[wave * 64 * 8]);
    // B tile: 256x32 = 1024 chunks, two per thread
#pragma unroll
    for (int i = 0; i < 2; ++i) {
      int c = i * 512 + tid;
      int r = c >> 2, k8 = (c & 3) * 8;
      gload_lds16(Bt + (long)r * 512 + k0 + k8, &Bs[(i * 512 + wave * 64) * 8]);
    }
    __syncthreads();
    bf16x8 af[4], bfr[4];
#pragma unroll
    for (int m = 0; m < 4; ++m)
      af[m] = *(const bf16x8*)&As[(wr * 64 + m * 16 + lr) * 32 + lh * 8];
#pragma unroll
    for (int n = 0; n < 4; ++n)
      bfr[n] = *(const bf16x8*)&Bs[(wc * 64 + n * 16 + lr) * 32 + lh * 8];
#pragma unroll
    for (int m = 0; m < 4; ++m)
#pragma unroll
      for (int n = 0; n < 4; ++n)
        acc[m][n] =
            __builtin_amdgcn_mfma_f32_16x16x32_bf16(af[m], bfr[n], acc[m][n], 0, 0, 0);
    __syncthreads();
  }

  float bv[4], w2v[4];
#pragma unroll
  for (int n = 0; n < 4; ++n) {
    int cc = wc * 64 + n * 16 + lr;
    bv[n] = bias[cc];
    w2v[n] = bf2f(w2[cc]);
  }
#pragma unroll
  for (int m = 0; m < 4; ++m) {
#pragma unroll
    for (int r = 0; r < 4; ++r) {
      float s = 0.f;
#pragma unroll
      for (int n = 0; n < 4; ++n) {
        float v = fmaxf(acc[m][n][r] + bv[n], 0.f);
        s += v * w2v[n];
      }
#pragma unroll
      for (int off = 1; off < 16; off <<= 1) s += __shfl_xor(s, off);
      if (lr == 0) part[wc][wr * 64 + m * 16 + lh * 4 + r] = s;
    }
  }
  __syncthreads();
  if (tid < 128) {
    float logit = part[0][tid] + part[1][tid] + part[2][tid] + part[3][tid] +
                  Sb2[p];
    float s = 1.f / (1.f + expf(-logit));
    s = fmaxf(s, 1e-9f);
    float r = (1.f - s) / s;
    long n = (long)r0 + row0 + tid;
    int yv = y[n];
    float mf = (yv == pairs[p * 2] || yv == pairs[p * 2 + 1]) ? 1.f : 0.f;
    outR[(long)p * NE + n] = r * mf;
    outS[(long)p * NE + n] = s * mf;
    outM[(long)p * NE + n] = mf;
  }
}

extern "C" void kernel_launch(void* const* d_in, const int* in_sizes, int n_in,
                              void* d_out, int out_size, void* d_ws, size_t ws_size,
                              hipStream_t stream) {
  const float* x   = (const float*)d_in[0];
  const int*   y   = (const int*)d_in[1];
  const int*   prs = (const int*)d_in[2];
  const float* W0  = (const float*)d_in[3];
  const float* b0  = (const float*)d_in[4];
  const float* W1  = (const float*)d_in[5];
  const float* b1  = (const float*)d_in[6];
  const float* W2  = (const float*)d_in[7];
  const float* b2  = (const float*)d_in[8];
  const float* SW0 = (const float*)d_in[9];
  const float* Sb0 = (const float*)d_in[10];
  const float* SW1 = (const float*)d_in[11];
  const float* Sb1 = (const float*)d_in[12];
  const float* SW2 = (const float*)d_in[13];
  const float* Sb2 = (const float*)d_in[14];

  uint8_t* ws = (uint8_t*)d_ws;
  size_t off = 0;
  auto take = [&](size_t bytes) -> void* {
    void* ptr = ws + off;
    off = (off + bytes + 255) & ~(size_t)255;
    return ptr;
  };
  unsigned short* W0t  = (unsigned short*)take((size_t)64 * 512 * 2);
  unsigned short* W1t  = (unsigned short*)take((size_t)512 * 512 * 2);
  unsigned short* W2t  = (unsigned short*)take((size_t)512 * 512 * 2);
  unsigned short* SW0t = (unsigned short*)take((size_t)3 * 512 * 512 * 2);
  unsigned short* SW1t = (unsigned short*)take((size_t)3 * 256 * 512 * 2);
  unsigned short* SW2b = (unsigned short*)take((size_t)3 * 256 * 2);
  unsigned short* Xb   = (unsigned short*)take((size_t)NE * 64 * 2);
  // A3 = [P][CHUNK][512] bf16 (100.7 MB). T0/T1 alias its first two thirds:
  // they are dead by the time SW0 writes A3.
  unsigned short* A3   = (unsigned short*)take((size_t)3 * CHUNK * 512 * 2);
  unsigned short* T0   = A3;
  unsigned short* T1   = A3 + (size_t)CHUNK * 512;
  unsigned short* bufR = (unsigned short*)take((size_t)CHUNK * 512 * 2);

  float* out   = (float*)d_out;
  float* outRe = out;
  float* outR  = out + (size_t)NE * 512;
  float* outS  = outR + (size_t)3 * NE;
  float* outM  = outS + (size_t)3 * NE;

  // ---- prep: weights -> bf16 transposed, x -> relu bf16 ----
  transpose_cvt<<<dim3(128, 1), 256, 0, stream>>>(W0, W0t, 64, 512);
  transpose_cvt<<<dim3(1024, 1), 256, 0, stream>>>(W1, W1t, 512, 512);
  transpose_cvt<<<dim3(1024, 1), 256, 0, stream>>>(W2, W2t, 512, 512);
  transpose_cvt<<<dim3(1024, 3), 256, 0, stream>>>(SW0, SW0t, 512, 512);
  transpose_cvt<<<dim3(512, 3), 256, 0, stream>>>(SW1, SW1t, 512, 256);
  transpose_cvt<<<dim3(1, 3), 256, 0, stream>>>(SW2, SW2b, 256, 1);
  relu_cvt_x<<<dim3(NE * 64 / 4 / 256), 256, 0, stream>>>((const float4*)x,
                                                          (ushort4*)Xb);

  for (int c = 0; c < NE / CHUNK; ++c) {
    size_t r0 = (size_t)c * CHUNK;
    // trunk: Xb -> T0 -> T1 -> (repr fp32, bufR bf16)
    gemm_bf16<<<dim3(CHUNK / 128, 4, 1), 256, 0, stream>>>(
        Xb + r0 * 64, 0, W0t, 0, b0, 0, nullptr, T0, 0, 64, 512);
    gemm_bf16<<<dim3(CHUNK / 128, 4, 1), 256, 0, stream>>>(
        T0, 0, W1t, 0, b1, 0, nullptr, T1, 0, 512, 512);
    gemm_bf16<<<dim3(CHUNK / 128, 4, 1), 256, 0, stream>>>(
        T1, 0, W2t, 0, b2, 0, outRe + r0 * 512, bufR, 0, 512, 512);
    // SW0, batched over p: bufR -> A3[p] (clobbers T0/T1, which are dead)
    gemm_bf16<<<dim3(CHUNK / 128, 4, 3), 256, 0, stream>>>(
        bufR, 0, SW0t, (long)512 * 512, Sb0, 512, nullptr, A3,
        (long)CHUNK * 512, 512, 512);
    // SW1 + head, batched over p: A3[p] -> outputs
    gemm_sw1_head<<<dim3(CHUNK / 128, 1, 3), 512, 0, stream>>>(
        A3, SW1t, Sb1, SW2b, Sb2, y, prs, (int)r0, outR, outS, outM);
  }
}